// Round 4
// baseline (81.825 us; speedup 1.0000x reference)
//
#include <hip/hip_runtime.h>
#include <hip/hip_bf16.h>

// TSM temporal shift + 1x1 conv (256->256) fused as bf16 MFMA GEMM.
// x: [128, 256, 28, 28] f32, w: [256, 256] f32, out: [128, 256, 28, 28] f32.
// out[n,o,p] = sum_c W[o,c] * Y_n[c,p],
//   Y_n[c,p] = x[n-1,c,p] (c<32, t>0), x[n+1,c,p] (32<=c<64, t<7), x[n,c,p] else.
//
// R4: persistent double-buffered pipeline over flattened (n,p) column space.
//  - 512 resident blocks (2/CU), grid-stride over 3136 tiles of 32 columns.
//  - Prefetch tile t+1 via asm global_load_dwordx4 (cannot be sunk/deleted),
//    compute tile t, store, then s_waitcnt vmcnt(16) (drains the 4 prefetch
//    loads, leaves the 16 output stores in flight) + sched_barrier + ds_write.
//  - LDS f32 [2][32][260]; +4 pad makes B-frag ds_read_b128 conflict-free.
//  - Clip-edge zeros via address redirect to a zeroed 256B region of d_ws.

#define CDIM 256
#define HWPX 784
#define FR_STRIDE (CDIM * HWPX)   // 200704 floats per frame
#define QTOT (128 * HWPX)         // 100352 output columns
#define TPX 32                    // columns per tile
#define NTILES (QTOT / TPX)       // 3136
#define NBLK 512
#define LROW 260                  // f32 per LDS pixel-row (+4 pad)

using bf16x8 = __attribute__((ext_vector_type(8))) short;
using f32x4  = __attribute__((ext_vector_type(4))) float;

static __device__ __forceinline__ unsigned int pk2(float lo, float hi) {
    union { __hip_bfloat162 h; unsigned int u; } cv;
    cv.h = __float22bfloat162_rn(make_float2(lo, hi));
    return cv.u;
}

// ---- W f32 -> bf16 row-major (one-shot, 256KB read / 128KB write) ----------
__global__ void wconv(const float* __restrict__ w, unsigned short* __restrict__ wb) {
    const int i = (blockIdx.x * 256 + threadIdx.x) * 4;
    f32x4 v = *(const f32x4*)(w + i);
    *(uint2*)(wb + i) = make_uint2(pk2(v[0], v[1]), pk2(v[2], v[3]));
}

__global__ __launch_bounds__(512, 4)   // <=128 VGPR, 2 blocks/CU (LDS 66.5KB)
void tsm_pipe(const float* __restrict__ x,
              const unsigned short* __restrict__ wb,
              const float* __restrict__ zbuf,
              float* __restrict__ out) {
    __shared__ __align__(16) float yb[2][TPX * LROW];

    const int tid  = threadIdx.x;
    const int lane = tid & 63;
    const int wv   = tid >> 6;        // 8 waves, each owns 32 out-channels
    const int g    = lane >> 4;
    const int ol   = lane & 15;

    // ---- staging constants (per-thread, tile-invariant) -------------------
    const int vp  = tid & 7;          // vec4 slot within the 32-col row
    const int cb0 = tid >> 3;         // channel for j=0; c_j = cb0 + 64j
    int  cj[4]; long coff[4]; int dj[4];
    #pragma unroll
    for (int j = 0; j < 4; ++j) {
        const int c = cb0 + j * 64;
        cj[j]   = c;
        coff[j] = (long)c * HWPX;
        dj[j]   = (c < 32) ? -1 : (c < 64 ? 1 : 0);
    }

    int t   = blockIdx.x;
    int buf = 0;
    f32x4 rv[4];

    // ---- LOADS(t): issue 4 prefetch vec4 loads (asm: cannot sink) ---------
    #define LOADS(TT)                                                          \
    {                                                                          \
        const int gp  = (TT) * TPX + vp * 4;                                   \
        const int nf  = gp / HWPX;                                             \
        const int pin = gp - nf * HWPX;                                        \
        const int tf  = nf & 7;                                                \
        const float* base = x + (size_t)nf * FR_STRIDE + pin;                  \
        _Pragma("unroll")                                                      \
        for (int j = 0; j < 4; ++j) {                                          \
            const bool valid = (dj[j] == 0) ? true                             \
                             : (dj[j] < 0 ? (tf > 0) : (tf < 7));              \
            const float* sp = valid ? (base + (long)dj[j] * FR_STRIDE + coff[j])\
                                    : zbuf;                                    \
            asm volatile("global_load_dwordx4 %0, %1, off"                     \
                         : "=v"(rv[j]) : "v"(sp));                             \
        }                                                                      \
    }

    #define WRITE_LDS(B)                                                       \
    {                                                                          \
        float* d = &yb[(B)][0];                                                \
        _Pragma("unroll")                                                      \
        for (int j = 0; j < 4; ++j) {                                          \
            const int base = (vp * 4) * LROW + cj[j];                          \
            _Pragma("unroll")                                                  \
            for (int e = 0; e < 4; ++e) d[base + e * LROW] = rv[j][e];         \
        }                                                                      \
    }

    // ---- prologue: stage tile t into buf 0 --------------------------------
    LOADS(t);
    asm volatile("s_waitcnt vmcnt(0)" ::: "memory");
    __builtin_amdgcn_sched_barrier(0);
    WRITE_LDS(0);
    __syncthreads();

    while (1) {
        const int  tn   = t + NBLK;
        const bool more = tn < NTILES;
        if (more) LOADS(tn);

        // ---- compute tile t from yb[buf] ----------------------------------
        f32x4 acc[2][2];
        #pragma unroll
        for (int m = 0; m < 2; ++m)
            #pragma unroll
            for (int nn = 0; nn < 2; ++nn)
                acc[m][nn] = f32x4{0.f, 0.f, 0.f, 0.f};

        const float* yr = &yb[buf][0];
        #pragma unroll
        for (int kk = 0; kk < 8; ++kk) {
            const int ca = kk * 32 + g * 8;      // k = g*8+j for A and B
            const bf16x8 af0 = *(const bf16x8*)&wb[(size_t)(wv * 32 + ol) * CDIM + ca];
            const bf16x8 af1 = *(const bf16x8*)&wb[(size_t)(wv * 32 + 16 + ol) * CDIM + ca];
            #pragma unroll
            for (int nn = 0; nn < 2; ++nn) {
                const int pl = nn * 16 + ol;     // B col = pixel on lane&15
                const float* yp = yr + pl * LROW + ca;
                const f32x4 y0 = *(const f32x4*)yp;
                const f32x4 y1 = *(const f32x4*)(yp + 4);
                union { bf16x8 v; unsigned int u[4]; } cvb;
                cvb.u[0] = pk2(y0[0], y0[1]);
                cvb.u[1] = pk2(y0[2], y0[3]);
                cvb.u[2] = pk2(y1[0], y1[1]);
                cvb.u[3] = pk2(y1[2], y1[3]);
                acc[0][nn] = __builtin_amdgcn_mfma_f32_16x16x32_bf16(af0, cvb.v, acc[0][nn], 0, 0, 0);
                acc[1][nn] = __builtin_amdgcn_mfma_f32_16x16x32_bf16(af1, cvb.v, acc[1][nn], 0, 0, 0);
            }
        }

        // ---- store tile t (16 dword stores, left in flight) ---------------
        #pragma unroll
        for (int nn = 0; nn < 2; ++nn) {
            const int q  = t * TPX + nn * 16 + ol;
            const int nf = q / HWPX;
            const int p  = q - nf * HWPX;
            float* ob = out + (size_t)nf * FR_STRIDE + p;
            #pragma unroll
            for (int m = 0; m < 2; ++m)
                #pragma unroll
                for (int r = 0; r < 4; ++r) {
                    const int o = wv * 32 + m * 16 + g * 4 + r;
                    ob[(size_t)o * HWPX] = acc[m][nn][r];
                }
        }

        if (!more) break;
        __syncthreads();                          // all waves done reading yb[buf^1]
        // drain the 4 prefetch loads; 16 newest (stores) may stay in flight
        asm volatile("s_waitcnt vmcnt(16)" ::: "memory");
        __builtin_amdgcn_sched_barrier(0);
        WRITE_LDS(buf ^ 1);
        __syncthreads();                          // writes visible
        buf ^= 1;
        t = tn;
    }
    #undef LOADS
    #undef WRITE_LDS
}

// ---- fallback (no workspace): R3 kernel, known-correct ---------------------
#define P_TILE 112
#define LDS_STRIDE 264
__global__ __launch_bounds__(512, 4)
void tsm_fallback(const float* __restrict__ x, const float* __restrict__ w,
                  float* __restrict__ out) {
    __shared__ __align__(16) unsigned short ylds[P_TILE * LDS_STRIDE];
    const int n = blockIdx.x, tile = blockIdx.y, p0 = tile * P_TILE;
    const int tid = threadIdx.x, tf = n & 7;
    f32x4 v0[7], v1[7]; int cps[7], pvs[7];
    #pragma unroll
    for (int i = 0; i < 7; ++i) {
        const int idx = tid + i * 512, cp = idx / 28, pv = idx - cp * 28;
        cps[i] = cp; pvs[i] = pv;
        const int c0 = cp * 2;
        int nsrc; bool valid;
        if (c0 < 32)      { nsrc = n - 1; valid = (tf > 0); }
        else if (c0 < 64) { nsrc = n + 1; valid = (tf < 7); }
        else              { nsrc = n;     valid = true; }
        const float* src = x + ((size_t)(valid ? nsrc : n) * CDIM + c0) * HWPX + p0 + pv * 4;
        f32x4 a = {0,0,0,0}, b = {0,0,0,0};
        if (valid) { a = *(const f32x4*)src; b = *(const f32x4*)(src + HWPX); }
        v0[i] = a; v1[i] = b;
    }
    #pragma unroll
    for (int i = 0; i < 7; ++i) {
        const int c0 = cps[i] * 2, pv = pvs[i];
        const int cc = c0 ^ ((pv & 7) << 3);
        const int rb = pv * 4 * LDS_STRIDE + cc;
        #pragma unroll
        for (int r = 0; r < 4; ++r)
            *(unsigned int*)&ylds[rb + r * LDS_STRIDE] = pk2(v0[i][r], v1[i][r]);
    }
    __syncthreads();
    const int lane = tid & 63, wv = tid >> 6, g = lane >> 4, ol = lane & 15;
    f32x4 acc[2][7];
    #pragma unroll
    for (int m = 0; m < 2; ++m)
        #pragma unroll
        for (int nn = 0; nn < 7; ++nn) acc[m][nn] = f32x4{0,0,0,0};
    #pragma unroll
    for (int kk = 0; kk < 8; ++kk) {
        const int c = kk * 32 + g * 8;
        bf16x8 af[2];
        #pragma unroll
        for (int m = 0; m < 2; ++m) {
            const float* wp = w + (size_t)(wv * 32 + m * 16 + ol) * CDIM + c;
            f32x4 w0 = *(const f32x4*)wp, w1 = *(const f32x4*)(wp + 4);
            union { bf16x8 v; unsigned int u4[4]; } cv;
            cv.u4[0] = pk2(w0[0], w0[1]); cv.u4[1] = pk2(w0[2], w0[3]);
            cv.u4[2] = pk2(w1[0], w1[1]); cv.u4[3] = pk2(w1[2], w1[3]);
            af[m] = cv.v;
        }
        #pragma unroll
        for (int nn = 0; nn < 7; ++nn) {
            const int p = nn * 16 + ol;
            const int cc = c ^ (((p >> 2) & 7) << 3);
            const bf16x8 bf = *(const bf16x8*)&ylds[p * LDS_STRIDE + cc];
            #pragma unroll
            for (int m = 0; m < 2; ++m)
                acc[m][nn] = __builtin_amdgcn_mfma_f32_16x16x32_bf16(af[m], bf, acc[m][nn], 0, 0, 0);
        }
    }
    const size_t outbase = (size_t)n * CDIM * HWPX + p0 + ol;
    #pragma unroll
    for (int m = 0; m < 2; ++m)
        #pragma unroll
        for (int r = 0; r < 4; ++r) {
            const int o = wv * 32 + m * 16 + g * 4 + r;
            float* orow = out + outbase + (size_t)o * HWPX;
            #pragma unroll
            for (int nn = 0; nn < 7; ++nn) orow[nn * 16] = acc[m][nn][r];
        }
}

extern "C" void kernel_launch(void* const* d_in, const int* in_sizes, int n_in,
                              void* d_out, int out_size, void* d_ws, size_t ws_size,
                              hipStream_t stream) {
    const float* x = (const float*)d_in[0];
    const float* w = (const float*)d_in[1];
    float* out     = (float*)d_out;
    const size_t wb_bytes = (size_t)CDIM * CDIM * sizeof(unsigned short); // 128KB
    if (ws_size >= wb_bytes + 256) {
        unsigned short* wbuf = (unsigned short*)d_ws;
        float* zbuf = (float*)((char*)d_ws + wb_bytes);
        hipMemsetAsync(zbuf, 0, 256, stream);
        wconv<<<64, 256, 0, stream>>>(w, wbuf);
        tsm_pipe<<<NBLK, dim3(512, 1, 1), 0, stream>>>(x, wbuf, zbuf, out);
    } else {
        tsm_fallback<<<dim3(128, 7, 1), dim3(512, 1, 1), 0, stream>>>(x, w, out);
    }
}